// Round 9
// baseline (268.947 us; speedup 1.0000x reference)
//
#include <hip/hip_runtime.h>
#include <hip/hip_bf16.h>
#include <stdint.h>

// Problem shape (fixed by the reference): B=4, N=4096, D=1024, H=16, DK=64
#define B_  4
#define N_  4096
#define D_  1024
#define H_  16
#define DK_ 64
#define M_  (B_ * N_)   // 16384 rows

typedef __attribute__((ext_vector_type(8))) short  short8;   // 8 bf16 (4 VGPRs)
typedef __attribute__((ext_vector_type(4))) float  f32x4;
typedef __attribute__((ext_vector_type(4))) unsigned int u32x4;

__device__ __forceinline__ uint16_t f2bf(float f) {
  union { float f; uint32_t u; } v; v.f = f;
  uint32_t r = v.u + 0x7FFF + ((v.u >> 16) & 1);   // RNE
  return (uint16_t)(r >> 16);
}
__device__ __forceinline__ uint32_t f2bf2(float lo, float hi) {
  return (uint32_t)f2bf(lo) | ((uint32_t)f2bf(hi) << 16);
}
__device__ __forceinline__ float bf2f(uint16_t u) {
  union { uint32_t u; float f; } v; v.u = ((uint32_t)u) << 16;
  return v.f;
}

__device__ __forceinline__ void gload_lds16(const void* g, void* l) {
  __builtin_amdgcn_global_load_lds((const __attribute__((address_space(1))) void*)g,
                                   (__attribute__((address_space(3))) void*)l, 16, 0, 0);
}

#define S_BARRIER() __builtin_amdgcn_s_barrier()
#define FENCE_LGKM0() asm volatile("s_waitcnt lgkmcnt(0)" ::: "memory")
#define FENCE_VM4()   asm volatile("s_waitcnt vmcnt(4) lgkmcnt(0)" ::: "memory")
#define FENCE_VM0()   asm volatile("s_waitcnt vmcnt(0) lgkmcnt(0)" ::: "memory")

// ---------------------------------------------------------------- pack fp32->bf16
// 64 elems/thread, 8 unrolled iters. Plain loads (inputs are L3-resident across
// replays; nt bypassed that). Regular stores (bf16 re-read by GEMMs).
__global__ __launch_bounds__(256) void pack_bf16_kernel(
    const float* q, const float* k, const float* v,
    const float* wq, const float* wk, const float* wv, const float* wo,
    uint16_t* xq, uint16_t* xk, uint16_t* xv,
    uint16_t* bwq, uint16_t* bwk, uint16_t* bwv, uint16_t* bwo)
{
  const float* src; uint16_t* dst; int count;
  switch (blockIdx.y) {
    case 0: src = q;  dst = xq;  count = M_ * D_; break;
    case 1: src = k;  dst = xk;  count = M_ * D_; break;
    case 2: src = v;  dst = xv;  count = M_ * D_; break;
    case 3: src = wq; dst = bwq; count = D_ * D_; break;
    case 4: src = wk; dst = bwk; count = D_ * D_; break;
    case 5: src = wv; dst = bwv; count = D_ * D_; break;
    default: src = wo; dst = bwo; count = D_ * D_; break;
  }
  int base = blockIdx.x * 16384;               // 256 threads * 64 elems
  if (base >= count) return;                   // counts are multiples of 16384
  int t = threadIdx.x;
#pragma unroll
  for (int it = 0; it < 8; ++it) {
    int idx = base + it * 2048 + t * 8;
    f32x4 f0 = *(const f32x4*)(src + idx);
    f32x4 f1 = *(const f32x4*)(src + idx + 4);
    u32x4 o;
    o.x = f2bf2(f0.x, f0.y); o.y = f2bf2(f0.z, f0.w);
    o.z = f2bf2(f1.x, f1.y); o.w = f2bf2(f1.z, f1.w);
    *(u32x4*)(dst + idx) = o;
  }
}

// ---------------------------------------------------------------- shared epilogue
// C/D layout (m89-verified): col = lane&15, row = (lane>>4)*4 + reg
// EPI: 0 bf16 | 1 f32 | 2 bf16+row-softmax*0.5 | 3 bf16+col max/sumexp partials
template<int EPI>
__device__ __forceinline__ void gemm_epilogue(
    f32x4 (&acc)[8][4], int tid, int l, int lr, int kg, int wr, int wc,
    int brow, int bcol, const float* __restrict__ bias, void* __restrict__ C,
    float* __restrict__ pm, float* __restrict__ ps,
    float* sredm, float* sreds)
{
  if (EPI == 2) {
    // fused per-head row softmax * 0.5 (wave's 64 cols = one head)
    float bv[4];
#pragma unroll
    for (int ni = 0; ni < 4; ++ni) bv[ni] = bias[bcol * 256 + wc * 64 + ni * 16 + lr];
#pragma unroll
    for (int mi = 0; mi < 8; ++mi) {
#pragma unroll
      for (int j = 0; j < 4; ++j) {
        float v0 = acc[mi][0][j] + bv[0];
        float v1 = acc[mi][1][j] + bv[1];
        float v2 = acc[mi][2][j] + bv[2];
        float v3 = acc[mi][3][j] + bv[3];
        float m = fmaxf(fmaxf(v0, v1), fmaxf(v2, v3));
#pragma unroll
        for (int o = 1; o < 16; o <<= 1) m = fmaxf(m, __shfl_xor(m, o));
        float p0 = __expf(v0 - m), p1 = __expf(v1 - m);
        float p2 = __expf(v2 - m), p3 = __expf(v3 - m);
        float s = (p0 + p1) + (p2 + p3);
#pragma unroll
        for (int o = 1; o < 16; o <<= 1) s += __shfl_xor(s, o);
        float sc = 0.5f / s;                    // * batch**-0.5 = 0.5
        int row = brow * 256 + wr * 128 + mi * 16 + kg * 4 + j;
        uint16_t* out = (uint16_t*)C + (size_t)row * D_ + bcol * 256 + wc * 64 + lr;
        out[0]  = f2bf(p0 * sc);
        out[16] = f2bf(p1 * sc);
        out[32] = f2bf(p2 * sc);
        out[48] = f2bf(p3 * sc);
      }
    }
  } else if (EPI == 3) {
    // bf16 out + per-column (block's 256 rows) max / sum-exp partials
#pragma unroll
    for (int ni = 0; ni < 4; ++ni) {
      int coll = wc * 64 + ni * 16 + lr;
      int col = bcol * 256 + coll;
      float bvn = bias[col];
      float vals[8][4];
      float m = -1e30f;
#pragma unroll
      for (int mi = 0; mi < 8; ++mi)
#pragma unroll
        for (int j = 0; j < 4; ++j) {
          float val = acc[mi][ni][j] + bvn;
          vals[mi][j] = val;
          m = fmaxf(m, val);
          int row = brow * 256 + wr * 128 + mi * 16 + kg * 4 + j;
          ((uint16_t*)C)[(size_t)row * D_ + col] = f2bf(val);
        }
      m = fmaxf(m, __shfl_xor(m, 16));
      m = fmaxf(m, __shfl_xor(m, 32));
      float s = 0.f;
#pragma unroll
      for (int mi = 0; mi < 8; ++mi)
#pragma unroll
        for (int j = 0; j < 4; ++j) s += __expf(vals[mi][j] - m);
      s += __shfl_xor(s, 16);
      s += __shfl_xor(s, 32);
      if (l < 16) {
        sredm[wr * 256 + coll] = m;
        sreds[wr * 256 + coll] = s;
      }
    }
    __syncthreads();
    if (tid < 256) {
      float m0 = sredm[tid], m1 = sredm[256 + tid];
      float s0 = sreds[tid], s1 = sreds[256 + tid];
      float m = fmaxf(m0, m1);
      float s = s0 * __expf(m0 - m) + s1 * __expf(m1 - m);
      pm[(size_t)brow * D_ + bcol * 256 + tid] = m;
      ps[(size_t)brow * D_ + bcol * 256 + tid] = s;
    }
  } else {
#pragma unroll
    for (int mi = 0; mi < 8; ++mi) {
#pragma unroll
      for (int ni = 0; ni < 4; ++ni) {
        int col = bcol * 256 + wc * 64 + ni * 16 + lr;
        float bv = bias[col];
#pragma unroll
        for (int j = 0; j < 4; ++j) {
          int row = brow * 256 + wr * 128 + mi * 16 + kg * 4 + j;
          float val = acc[mi][ni][j] + bv;
          if (EPI == 1) ((float*)C)[(size_t)row * D_ + col] = val;
          else          ((uint16_t*)C)[(size_t)row * D_ + col] = f2bf(val);
        }
      }
    }
  }
}

// ------------------------------------------------- shared 256x256 4-phase K-loop
// read-once schedule: a:Q00(A0*B0,12 reads) b:Q10(A1*B0,8) c:Q11(A1*B1,4)
// d:Q01(A0*B1,0) -- B halves kept in regs across adjacent phases (no re-reads,
// same register footprint). Staging slots/fences identical to round-4-proven.
__device__ __forceinline__ void gemm256_body(
    const uint16_t* __restrict__ A, const uint16_t* __restrict__ Wb,
    uint16_t* As, uint16_t* Bs,
    int tid, int w, int arow0, int bcrow0, int srcswz, int rsw,
    int lr, int kg, int wr, int wc, f32x4 (&acc)[8][4])
{
  const int NT = 16;
  auto stage_half = [&](const uint16_t* g, int row0, int kt, uint16_t* ldst, int h) {
#pragma unroll
    for (int i = 0; i < 2; ++i) {
      int lin = h * 16384 + i * 8192 + tid * 16;
      int src = lin ^ srcswz;
      const uint16_t* gp = g + (size_t)(row0 + (src >> 7)) * D_ + kt * 64 + ((src & 127) >> 1);
      uint16_t* lp = ldst + h * 8192 + i * 4096 + w * 512;
      gload_lds16(gp, lp);
    }
  };
  auto rdfrag = [&](const uint16_t* tile, int row, int ks) -> short8 {
    return *(const short8*)(tile + row * 64 + ((((ks << 2) | kg) ^ rsw) << 3));
  };

  stage_half(A, arow0, 0, As, 0);  stage_half(A, arow0, 0, As, 1);
  stage_half(Wb, bcrow0, 0, Bs, 0); stage_half(Wb, bcrow0, 0, Bs, 1);
  stage_half(A, arow0, 1, As + 16384, 0); stage_half(A, arow0, 1, As + 16384, 1);
  FENCE_VM4();
  S_BARRIER();

  short8 af0[4][2], af1[4][2], bfr[2][2];
  for (int t = 0; t < NT; ++t) {
    const int p = t & 1;
    uint16_t* Ap = As + p * 16384;
    uint16_t* Bp = Bs + p * 16384;
    uint16_t* Bn = Bs + (p ^ 1) * 16384;

    // ---- phase a: read A0 + B0; stage B[t+1].h0 -> Bn; MFMA Q00
#pragma unroll
    for (int mi = 0; mi < 4; ++mi)
#pragma unroll
      for (int ks = 0; ks < 2; ++ks)
        af0[mi][ks] = rdfrag(Ap, wr * 128 + mi * 16 + lr, ks);
#pragma unroll
    for (int ni = 0; ni < 2; ++ni)
#pragma unroll
      for (int ks = 0; ks < 2; ++ks)
        bfr[ni][ks] = rdfrag(Bp, wc * 64 + ni * 16 + lr, ks);
    if (t + 1 < NT) stage_half(Wb, bcrow0, t + 1, Bn, 0);
    S_BARRIER();
    __builtin_amdgcn_s_setprio(1);
#pragma unroll
    for (int mi = 0; mi < 4; ++mi)
#pragma unroll
      for (int ni = 0; ni < 2; ++ni)
#pragma unroll
        for (int ks = 0; ks < 2; ++ks)
          acc[mi][ni] = __builtin_amdgcn_mfma_f32_16x16x32_bf16(af0[mi][ks], bfr[ni][ks], acc[mi][ni], 0, 0, 0);
    __builtin_amdgcn_s_setprio(0);
    FENCE_LGKM0();
    S_BARRIER();

    // ---- phase b: read A1 (B0 kept in regs); stage B[t+1].h1; MFMA Q10
#pragma unroll
    for (int mi = 0; mi < 4; ++mi)
#pragma unroll
      for (int ks = 0; ks < 2; ++ks)
        af1[mi][ks] = rdfrag(Ap, wr * 128 + 64 + mi * 16 + lr, ks);
    if (t + 1 < NT) stage_half(Wb, bcrow0, t + 1, Bn, 1);
    S_BARRIER();
    __builtin_amdgcn_s_setprio(1);
#pragma unroll
    for (int mi = 0; mi < 4; ++mi)
#pragma unroll
      for (int ni = 0; ni < 2; ++ni)
#pragma unroll
        for (int ks = 0; ks < 2; ++ks)
          acc[mi + 4][ni] = __builtin_amdgcn_mfma_f32_16x16x32_bf16(af1[mi][ks], bfr[ni][ks], acc[mi + 4][ni], 0, 0, 0);
    __builtin_amdgcn_s_setprio(0);
    FENCE_LGKM0();
    S_BARRIER();

    // ---- phase c: read B1 (overwrites B0 regs); stage A[t+2].h0; MFMA Q11
#pragma unroll
    for (int ni = 0; ni < 2; ++ni)
#pragma unroll
      for (int ks = 0; ks < 2; ++ks)
        bfr[ni][ks] = rdfrag(Bp, wc * 64 + (ni + 2) * 16 + lr, ks);
    if (t + 2 < NT) stage_half(A, arow0, t + 2, Ap, 0);
    S_BARRIER();
    __builtin_amdgcn_s_setprio(1);
#pragma unroll
    for (int mi = 0; mi < 4; ++mi)
#pragma unroll
      for (int ni = 0; ni < 2; ++ni)
#pragma unroll
        for (int ks = 0; ks < 2; ++ks)
          acc[mi + 4][ni + 2] = __builtin_amdgcn_mfma_f32_16x16x32_bf16(af1[mi][ks], bfr[ni][ks], acc[mi + 4][ni + 2], 0, 0, 0);
    __builtin_amdgcn_s_setprio(0);
    FENCE_LGKM0();
    S_BARRIER();

    // ---- phase d: no ds_reads (A0,B1 in regs); stage A[t+2].h1; MFMA Q01
    if (t + 2 < NT) stage_half(A, arow0, t + 2, Ap, 1);
    S_BARRIER();
    __builtin_amdgcn_s_setprio(1);
#pragma unroll
    for (int mi = 0; mi < 4; ++mi)
#pragma unroll
      for (int ni = 0; ni < 2; ++ni)
#pragma unroll
        for (int ks = 0; ks < 2; ++ks)
          acc[mi][ni + 2] = __builtin_amdgcn_mfma_f32_16x16x32_bf16(af0[mi][ks], bfr[ni][ks], acc[mi][ni + 2], 0, 0, 0);
    __builtin_amdgcn_s_setprio(0);
    if (t <= 13)      { FENCE_VM4(); }
    else if (t == 14) { FENCE_VM0(); }
    else              { FENCE_LGKM0(); }
    S_BARRIER();
  }
}

// ------------------------------------------------- fused Q/K/V projection GEMM
// grid (4, 64, 3): z selects {Q: softmax epi, K: colstats epi, V: plain}.
__global__ __launch_bounds__(512, 2) void qkv_gemm256_kernel(
    const uint16_t* __restrict__ XQ, const uint16_t* __restrict__ XK,
    const uint16_t* __restrict__ XV,
    const uint16_t* __restrict__ WQ, const uint16_t* __restrict__ WK,
    const uint16_t* __restrict__ WV,
    const float* __restrict__ bq, const float* __restrict__ bk,
    const float* __restrict__ bv,
    uint16_t* __restrict__ QS, uint16_t* __restrict__ KP,
    uint16_t* __restrict__ VP,
    float* __restrict__ pm, float* __restrict__ ps)
{
  extern __shared__ uint16_t smem[];           // As[2][16384] | Bs[2][16384] | sred
  uint16_t* As = smem;
  uint16_t* Bs = smem + 32768;
  float* sredm = (float*)(smem + 65536);       // [2][256]
  float* sreds = sredm + 512;

  const int tid = threadIdx.x;
  const int w = tid >> 6, l = tid & 63;
  const int lr = l & 15, kg = l >> 4;
  const int wr = w >> 2, wc = w & 3;           // 2x4 wave grid
  const int rsw = lr & 7;
  const int srcswz = ((tid >> 3) & 7) << 4;

  const int flat = blockIdx.y * 4 + blockIdx.x;
  const int swzf = (flat & 7) * 32 + (flat >> 3);
  const int brow = swzf >> 2, bcol = swzf & 3;
  const int z = blockIdx.z;

  const uint16_t* A = (z == 0) ? XQ : (z == 1) ? XK : XV;
  const uint16_t* W = (z == 0) ? WQ : (z == 1) ? WK : WV;
  const float* bias = (z == 0) ? bq : (z == 1) ? bk : bv;
  void* C          = (z == 0) ? (void*)QS : (z == 1) ? (void*)KP : (void*)VP;

  f32x4 acc[8][4];
#pragma unroll
  for (int i = 0; i < 8; ++i)
#pragma unroll
    for (int j = 0; j < 4; ++j) acc[i][j] = (f32x4){0.f, 0.f, 0.f, 0.f};

  gemm256_body(A, W, As, Bs, tid, w, brow * 256, bcol * 256, srcswz, rsw,
               lr, kg, wr, wc, acc);

  if (z == 0)
    gemm_epilogue<2>(acc, tid, l, lr, kg, wr, wc, brow, bcol, bias, C, pm, ps, sredm, sreds);
  else if (z == 1)
    gemm_epilogue<3>(acc, tid, l, lr, kg, wr, wc, brow, bcol, bias, C, pm, ps, sredm, sreds);
  else
    gemm_epilogue<0>(acc, tid, l, lr, kg, wr, wc, brow, bcol, bias, C, pm, ps, sredm, sreds);
}

// ------------------------------------------------- out-projection GEMM (batched W)
__global__ __launch_bounds__(512, 2) void gemm256_kernel(
    const uint16_t* __restrict__ A,
    const uint16_t* __restrict__ W,
    const float* __restrict__ bias,
    void* __restrict__ C)
{
  extern __shared__ uint16_t smem[];
  uint16_t* As = smem;
  uint16_t* Bs = smem + 32768;

  const int tid = threadIdx.x;
  const int w = tid >> 6, l = tid & 63;
  const int lr = l & 15, kg = l >> 4;
  const int wr = w >> 2, wc = w & 3;
  const int rsw = lr & 7;
  const int srcswz = ((tid >> 3) & 7) << 4;

  const int flat = blockIdx.y * 4 + blockIdx.x;
  const int swzf = (flat & 7) * 32 + (flat >> 3);
  const int brow = swzf >> 2, bcol = swzf & 3;

  const uint16_t* Wb = W + (size_t)(brow >> 4) * ((size_t)D_ * D_);

  f32x4 acc[8][4];
#pragma unroll
  for (int i = 0; i < 8; ++i)
#pragma unroll
    for (int j = 0; j < 4; ++j) acc[i][j] = (f32x4){0.f, 0.f, 0.f, 0.f};

  gemm256_body(A, Wb, As, Bs, tid, w, brow * 256, bcol * 256, srcswz, rsw,
               lr, kg, wr, wc, acc);

  gemm_epilogue<1>(acc, tid, l, lr, kg, wr, wc, brow, bcol, bias, C,
                   nullptr, nullptr, nullptr, nullptr);
}

// ------------------------------------------------- K column-softmax finalize
__global__ __launch_bounds__(256) void colstats_final_kernel(
    const float* __restrict__ pm, const float* __restrict__ ps,
    float* __restrict__ cmax, float* __restrict__ cinv)
{
  int f = blockIdx.x * 256 + threadIdx.x;     // b*1024 + col, 4096 total
  int b = f >> 10, col = f & 1023;
  float m = -1e30f;
  for (int c = 0; c < 16; ++c) m = fmaxf(m, pm[(size_t)(b * 16 + c) * D_ + col]);
  float s = 0.f;
  for (int c = 0; c < 16; ++c)
    s += ps[(size_t)(b * 16 + c) * D_ + col] * __expf(pm[(size_t)(b * 16 + c) * D_ + col] - m);
  cmax[f] = m;
  cinv[f] = 1.f / s;
}

// ------------------------------------------------- ctx[b,h] = softmax_n(K)^T @ V
__global__ __launch_bounds__(256) void ctx_partial_kernel(
    const uint16_t* __restrict__ kp, const uint16_t* __restrict__ vp,
    const float* __restrict__ cmax, const float* __restrict__ cinv,
    float* __restrict__ ctxp)
{
  __shared__ float wk[64][64];
  __shared__ float vt[64][64];
  __shared__ float cm[64], ci[64];
  int t = threadIdx.x;
  int nchunk = blockIdx.x, h = blockIdx.y, b = blockIdx.z;
  if (t < 64) {
    cm[t] = cmax[b * D_ + h * 64 + t];
    ci[t] = cinv[b * D_ + h * 64 + t];
  }
  __syncthreads();
  int d0 = (t >> 4) * 4, e0 = (t & 15) * 4;
  f32x4 acc[4];
#pragma unroll
  for (int i = 0; i < 4; ++i) acc[i] = (f32x4){0.f, 0.f, 0.f, 0.f};

  for (int tt = 0; tt < 8; ++tt) {
    int n0 = nchunk * 512 + tt * 64;
#pragma unroll
    for (int i = 0; i < 4; ++i) {
      int qq = i * 256 + t;
      int r = qq >> 4, c4 = (qq & 15) * 4;
      size_t gi = (size_t)(b * N_ + n0 + r) * D_ + h * 64 + c4;
      union { uint16_t s[4]; uint2 u; } kk, vv;
      kk.u = *(const uint2*)(kp + gi);
      vv.u = *(const uint2*)(vp + gi);
#pragma unroll
      for (int j = 0; j < 4; ++j) {
        wk[r][c4 + j] = __expf(bf2f(kk.s[j]) - cm[c4 + j]) * ci[c4 + j];
        vt[r][c4 + j] = bf2f(vv.s[j]);
      }
    }
    __syncthreads();
#pragma unroll 8
    for (int n = 0; n < 64; ++n) {
      f32x4 wv = *(const f32x4*)&wk[n][d0];
      f32x4 vv4 = *(const f32x4*)&vt[n][e0];
#pragma unroll
      for (int di = 0; di < 4; ++di) acc[di] = acc[di] + vv4 * wv[di];
    }
    __syncthreads();
  }
  float* out = ctxp + (size_t)(nchunk * 64 + b * 16 + h) * 4096;
#pragma unroll
  for (int di = 0; di < 4; ++di)
    *(f32x4*)(out + (d0 + di) * 64 + e0) = acc[di];
}

__global__ __launch_bounds__(256) void ctx_reduce_kernel(
    const float* __restrict__ ctxp, float* __restrict__ ctx)
{
  int o = (blockIdx.x * 256 + threadIdx.x) * 4;  // 262144 elems
  f32x4 s = (f32x4){0.f, 0.f, 0.f, 0.f};
  for (int c = 0; c < 8; ++c) s = s + *(const f32x4*)(ctxp + (size_t)c * 262144 + o);
  *(f32x4*)(ctx + o) = s;
}

// ---------------- W2T[b][o][h*64+d] = sum_e ctx[b,h][d][e] * Wo[o][h*64+e]
__global__ __launch_bounds__(256) void w2t_kernel(
    const float* __restrict__ ctx,      // [(b*16+h)][64 d][64 e]
    const uint16_t* __restrict__ wo,    // [1024 o][1024] bf16
    uint16_t* __restrict__ w2t)         // [b][1024 o][1024 j]
{
  __shared__ float ctxL[64][65];
  __shared__ float woL[64][65];
  int t = threadIdx.x;
  int otile = blockIdx.x, h = blockIdx.y, b = blockIdx.z;
  const float* csrc = ctx + (size_t)(b * 16 + h) * 4096;
#pragma unroll
  for (int i = 0; i < 4; ++i) {
    int idx = (i * 256 + t) * 4;
    int r = idx >> 6, c = idx & 63;
    f32x4 cv = *(const f32x4*)(csrc + idx);
    union { uint16_t s[4]; uint2 u; } wv;
    wv.u = *(const uint2*)(wo + (size_t)(otile * 64 + r) * D_ + h * 64 + c);
#pragma unroll
    for (int j = 0; j < 4; ++j) {
      ctxL[r][c + j] = cv[j];
      woL[r][c + j] = bf2f(wv.s[j]);
    }
  }
  __syncthreads();
  int ol = (t & 15) * 4, dl = (t >> 4) * 4;
  float acc[4][4];
#pragma unroll
  for (int i = 0; i < 4; ++i)
#pragma unroll
    for (int j = 0; j < 4; ++j) acc[i][j] = 0.f;
#pragma unroll 4
  for (int e = 0; e < 64; ++e) {
    float cv[4], wv[4];
#pragma unroll
    for (int i = 0; i < 4; ++i) { cv[i] = ctxL[dl + i][e]; wv[i] = woL[ol + i][e]; }
#pragma unroll
    for (int di = 0; di < 4; ++di)
#pragma unroll
      for (int oi = 0; oi < 4; ++oi) acc[di][oi] += cv[di] * wv[oi];
  }
  uint16_t* dst = w2t + (size_t)b * D_ * D_ + (size_t)(otile * 64) * D_ + h * 64;
#pragma unroll
  for (int oi = 0; oi < 4; ++oi) {
    union { uint16_t s[4]; uint2 u; } o4;
#pragma unroll
    for (int di = 0; di < 4; ++di) o4.s[di] = f2bf(acc[di][oi]);
    *(uint2*)(dst + (size_t)(ol + oi) * D_ + dl) = o4.u;
  }
}

// ---------------------------------------------------------------- launch
extern "C" void kernel_launch(void* const* d_in, const int* in_sizes, int n_in,
                              void* d_out, int out_size, void* d_ws, size_t ws_size,
                              hipStream_t stream)
{
  const float* q  = (const float*)d_in[0];
  const float* k  = (const float*)d_in[1];
  const float* v  = (const float*)d_in[2];
  const float* Wq = (const float*)d_in[3];
  const float* bq = (const float*)d_in[4];
  const float* Wk = (const float*)d_in[5];
  const float* bk = (const float*)d_in[6];
  const float* Wv = (const float*)d_in[7];
  const float* bv = (const float*)d_in[8];
  const float* Wo = (const float*)d_in[9];
  const float* bo = (const float*)d_in[10];

  char* ws = (char*)d_ws;
  const size_t XB = (size_t)M_ * D_ * 2;       // 32 MB bf16 activations
  const size_t WB = (size_t)D_ * D_ * 2;       // 2 MB bf16 weights
  uint16_t* XQ  = (uint16_t*)(ws);
  uint16_t* XK  = (uint16_t*)(ws + XB);
  uint16_t* XV  = (uint16_t*)(ws + 2 * XB);
  uint16_t* WQb = (uint16_t*)(ws + 3 * XB);
  uint16_t* WKb = (uint16_t*)(ws + 3 * XB + WB);
  uint16_t* WVb = (uint16_t*)(ws + 3 * XB + 2 * WB);
  uint16_t* WOb = (uint16_t*)(ws + 3 * XB + 3 * WB);
  uint16_t* QS  = (uint16_t*)(ws + 3 * XB + 4 * WB);   // softmaxed Q proj (bf16)
  uint16_t* KP  = (uint16_t*)(ws + 4 * XB + 4 * WB);
  uint16_t* VP  = (uint16_t*)(ws + 5 * XB + 4 * WB);
  // overlays (phase-ordered reuse):
  //  - K-stats partials live in d_out (dead until the final out-GEMM, which
  //    overwrites every element; consumed by colstats_final before that)
  float* pm = (float*)d_out;                      // 256 KB
  float* ps = (float*)((char*)d_out + (256 << 10)); // 256 KB
  //  - stats/ctx live in XK (dead after fused QKV GEMM reads it)
  float* cmax = (float*)XK;                       // 16 KB
  float* cinv = (float*)((char*)XK + (16 << 10)); // 16 KB
  float* ctxp = (float*)((char*)XK + (1 << 20));  // 8 MB
  float* ctx  = (float*)((char*)XK + (9 << 20));  // 1 MB
  //  - W2T lives in XQ (dead after fused QKV GEMM reads it)
  uint16_t* W2T = XQ;                             // 8 MB

  const size_t LDSB = 135168;                     // 128KB tiles + 4KB sred

  // 1) pack inputs + weights to bf16 (plain loads, 64 elems/thread)
  pack_bf16_kernel<<<dim3(1024, 7), 256, 0, stream>>>(
      q, k, v, Wq, Wk, Wv, Wo, XQ, XK, XV, WQb, WKb, WVb, WOb);

  // 2) fused Q/K/V projections (one launch, 768 blocks)
  qkv_gemm256_kernel<<<dim3(4, 64, 3), 512, LDSB, stream>>>(
      XQ, XK, XV, WQb, WKb, WVb, bq, bk, bv, QS, KP, VP, pm, ps);

  // 3) finalize K column-softmax stats (16 chunks of 256 rows per batch)
  colstats_final_kernel<<<16, 256, 0, stream>>>(pm, ps, cmax, cinv);

  // 4) ctx = softmax_n(K)^T V per head
  ctx_partial_kernel<<<dim3(8, H_, B_), 256, 0, stream>>>(KP, VP, cmax, cinv, ctxp);
  ctx_reduce_kernel<<<256, 256, 0, stream>>>(ctxp, ctx);

  // 5) fold block-diagonal ctx into output projection: W2T_b = (BD_b @ Wo^T)^T
  w2t_kernel<<<dim3(16, 16, 4), 256, 0, stream>>>(ctx, WOb, W2T);

  // 6) out = QS @ W2T_b^T + bo   (f32 out, per-batch weights)
  gemm256_kernel<<<dim3(4, 64), 512, LDSB, stream>>>(QS, W2T, bo, d_out);
}

// Round 10
// 261.775 us; speedup vs baseline: 1.0274x; 1.0274x over previous
//
#include <hip/hip_runtime.h>
#include <hip/hip_bf16.h>
#include <stdint.h>

// Problem shape (fixed by the reference): B=4, N=4096, D=1024, H=16, DK=64
#define B_  4
#define N_  4096
#define D_  1024
#define H_  16
#define DK_ 64
#define M_  (B_ * N_)   // 16384 rows

typedef __attribute__((ext_vector_type(8))) short  short8;   // 8 bf16 (4 VGPRs)
typedef __attribute__((ext_vector_type(4))) float  f32x4;
typedef __attribute__((ext_vector_type(4))) unsigned int u32x4;

__device__ __forceinline__ uint16_t f2bf(float f) {
  union { float f; uint32_t u; } v; v.f = f;
  uint32_t r = v.u + 0x7FFF + ((v.u >> 16) & 1);   // RNE
  return (uint16_t)(r >> 16);
}
__device__ __forceinline__ uint32_t f2bf2(float lo, float hi) {
  return (uint32_t)f2bf(lo) | ((uint32_t)f2bf(hi) << 16);
}
__device__ __forceinline__ float bf2f(uint16_t u) {
  union { uint32_t u; float f; } v; v.u = ((uint32_t)u) << 16;
  return v.f;
}

__device__ __forceinline__ void gload_lds16(const void* g, void* l) {
  __builtin_amdgcn_global_load_lds((const __attribute__((address_space(1))) void*)g,
                                   (__attribute__((address_space(3))) void*)l, 16, 0, 0);
}

#define S_BARRIER() __builtin_amdgcn_s_barrier()
#define FENCE_LGKM0() asm volatile("s_waitcnt lgkmcnt(0)" ::: "memory")
#define FENCE_VM4()   asm volatile("s_waitcnt vmcnt(4) lgkmcnt(0)" ::: "memory")
#define FENCE_VM0()   asm volatile("s_waitcnt vmcnt(0) lgkmcnt(0)" ::: "memory")

// ---------------------------------------------------------------- pack fp32->bf16
__global__ __launch_bounds__(256) void pack_bf16_kernel(
    const float* q, const float* k, const float* v,
    const float* wq, const float* wk, const float* wv, const float* wo,
    uint16_t* xq, uint16_t* xk, uint16_t* xv,
    uint16_t* bwq, uint16_t* bwk, uint16_t* bwv, uint16_t* bwo)
{
  const float* src; uint16_t* dst; int count;
  switch (blockIdx.y) {
    case 0: src = q;  dst = xq;  count = M_ * D_; break;
    case 1: src = k;  dst = xk;  count = M_ * D_; break;
    case 2: src = v;  dst = xv;  count = M_ * D_; break;
    case 3: src = wq; dst = bwq; count = D_ * D_; break;
    case 4: src = wk; dst = bwk; count = D_ * D_; break;
    case 5: src = wv; dst = bwv; count = D_ * D_; break;
    default: src = wo; dst = bwo; count = D_ * D_; break;
  }
  int base = blockIdx.x * 16384;               // 256 threads * 64 elems
  if (base >= count) return;                   // counts are multiples of 16384
  int t = threadIdx.x;
#pragma unroll
  for (int it = 0; it < 8; ++it) {
    int idx = base + it * 2048 + t * 8;
    f32x4 f0 = *(const f32x4*)(src + idx);
    f32x4 f1 = *(const f32x4*)(src + idx + 4);
    u32x4 o;
    o.x = f2bf2(f0.x, f0.y); o.y = f2bf2(f0.z, f0.w);
    o.z = f2bf2(f1.x, f1.y); o.w = f2bf2(f1.z, f1.w);
    *(u32x4*)(dst + idx) = o;
  }
}

// ---------------------------------------------------------------- shared epilogue
// C/D layout (m89-verified): col = lane&15, row = (lane>>4)*4 + reg
// EPI: 0 bf16 | 1 f32 | 2 bf16+row-softmax*0.5 | 3 bf16+col max/sumexp partials
template<int EPI>
__device__ __forceinline__ void gemm_epilogue(
    f32x4 (&acc)[8][4], int tid, int l, int lr, int kg, int wr, int wc,
    int brow, int bcol, const float* __restrict__ bias, void* __restrict__ C,
    float* __restrict__ pm, float* __restrict__ ps,
    float* sredm, float* sreds)
{
  if (EPI == 2) {
    float bv[4];
#pragma unroll
    for (int ni = 0; ni < 4; ++ni) bv[ni] = bias[bcol * 256 + wc * 64 + ni * 16 + lr];
#pragma unroll
    for (int mi = 0; mi < 8; ++mi) {
#pragma unroll
      for (int j = 0; j < 4; ++j) {
        float v0 = acc[mi][0][j] + bv[0];
        float v1 = acc[mi][1][j] + bv[1];
        float v2 = acc[mi][2][j] + bv[2];
        float v3 = acc[mi][3][j] + bv[3];
        float m = fmaxf(fmaxf(v0, v1), fmaxf(v2, v3));
#pragma unroll
        for (int o = 1; o < 16; o <<= 1) m = fmaxf(m, __shfl_xor(m, o));
        float p0 = __expf(v0 - m), p1 = __expf(v1 - m);
        float p2 = __expf(v2 - m), p3 = __expf(v3 - m);
        float s = (p0 + p1) + (p2 + p3);
#pragma unroll
        for (int o = 1; o < 16; o <<= 1) s += __shfl_xor(s, o);
        float sc = 0.5f / s;                    // * batch**-0.5 = 0.5
        int row = brow * 256 + wr * 128 + mi * 16 + kg * 4 + j;
        uint16_t* out = (uint16_t*)C + (size_t)row * D_ + bcol * 256 + wc * 64 + lr;
        out[0]  = f2bf(p0 * sc);
        out[16] = f2bf(p1 * sc);
        out[32] = f2bf(p2 * sc);
        out[48] = f2bf(p3 * sc);
      }
    }
  } else if (EPI == 3) {
#pragma unroll
    for (int ni = 0; ni < 4; ++ni) {
      int coll = wc * 64 + ni * 16 + lr;
      int col = bcol * 256 + coll;
      float bvn = bias[col];
      float vals[8][4];
      float m = -1e30f;
#pragma unroll
      for (int mi = 0; mi < 8; ++mi)
#pragma unroll
        for (int j = 0; j < 4; ++j) {
          float val = acc[mi][ni][j] + bvn;
          vals[mi][j] = val;
          m = fmaxf(m, val);
          int row = brow * 256 + wr * 128 + mi * 16 + kg * 4 + j;
          ((uint16_t*)C)[(size_t)row * D_ + col] = f2bf(val);
        }
      m = fmaxf(m, __shfl_xor(m, 16));
      m = fmaxf(m, __shfl_xor(m, 32));
      float s = 0.f;
#pragma unroll
      for (int mi = 0; mi < 8; ++mi)
#pragma unroll
        for (int j = 0; j < 4; ++j) s += __expf(vals[mi][j] - m);
      s += __shfl_xor(s, 16);
      s += __shfl_xor(s, 32);
      if (l < 16) {
        sredm[wr * 256 + coll] = m;
        sreds[wr * 256 + coll] = s;
      }
    }
    __syncthreads();
    if (tid < 256) {
      float m0 = sredm[tid], m1 = sredm[256 + tid];
      float s0 = sreds[tid], s1 = sreds[256 + tid];
      float m = fmaxf(m0, m1);
      float s = s0 * __expf(m0 - m) + s1 * __expf(m1 - m);
      pm[(size_t)brow * D_ + bcol * 256 + tid] = m;
      ps[(size_t)brow * D_ + bcol * 256 + tid] = s;
    }
  } else {
#pragma unroll
    for (int mi = 0; mi < 8; ++mi) {
#pragma unroll
      for (int ni = 0; ni < 4; ++ni) {
        int col = bcol * 256 + wc * 64 + ni * 16 + lr;
        float bv = bias[col];
#pragma unroll
        for (int j = 0; j < 4; ++j) {
          int row = brow * 256 + wr * 128 + mi * 16 + kg * 4 + j;
          float val = acc[mi][ni][j] + bv;
          if (EPI == 1) ((float*)C)[(size_t)row * D_ + col] = val;
          else          ((uint16_t*)C)[(size_t)row * D_ + col] = f2bf(val);
        }
      }
    }
  }
}

// ------------------------------------------------- shared 256x256 4-phase K-loop
// read-once quadrant schedule (round-9) + hoisted staging addresses: 8 per-thread
// base pointers computed once; per stage just base + kt*64 (one v_add per load).
__device__ __forceinline__ void gemm256_body(
    const uint16_t* __restrict__ A, const uint16_t* __restrict__ Wb,
    uint16_t* As, uint16_t* Bs,
    int tid, int w, int arow0, int bcrow0, int srcswz, int rsw,
    int lr, int kg, int wr, int wc, f32x4 (&acc)[8][4])
{
  const int NT = 16;
  const uint16_t* gA[2][2];
  const uint16_t* gB[2][2];
  int lOff[2][2];
#pragma unroll
  for (int h = 0; h < 2; ++h)
#pragma unroll
    for (int i = 0; i < 2; ++i) {
      int lin = h * 16384 + i * 8192 + tid * 16;
      int src = lin ^ srcswz;
      size_t rowoff = (size_t)(src >> 7) * D_ + ((src & 127) >> 1);
      gA[h][i] = A + (size_t)arow0 * D_ + rowoff;
      gB[h][i] = Wb + (size_t)bcrow0 * D_ + rowoff;
      lOff[h][i] = h * 8192 + i * 4096 + w * 512;
    }
  auto stageA = [&](int kt, uint16_t* ldst, int h) {
    gload_lds16(gA[h][0] + kt * 64, ldst + lOff[h][0]);
    gload_lds16(gA[h][1] + kt * 64, ldst + lOff[h][1]);
  };
  auto stageB = [&](int kt, uint16_t* ldst, int h) {
    gload_lds16(gB[h][0] + kt * 64, ldst + lOff[h][0]);
    gload_lds16(gB[h][1] + kt * 64, ldst + lOff[h][1]);
  };
  auto rdfrag = [&](const uint16_t* tile, int row, int ks) -> short8 {
    return *(const short8*)(tile + row * 64 + ((((ks << 2) | kg) ^ rsw) << 3));
  };

  stageA(0, As, 0); stageA(0, As, 1);
  stageB(0, Bs, 0); stageB(0, Bs, 1);
  stageA(1, As + 16384, 0); stageA(1, As + 16384, 1);
  FENCE_VM4();
  S_BARRIER();

  short8 af0[4][2], af1[4][2], bfr[2][2];
  for (int t = 0; t < NT; ++t) {
    const int p = t & 1;
    uint16_t* Ap = As + p * 16384;
    uint16_t* Bp = Bs + p * 16384;
    uint16_t* Bn = Bs + (p ^ 1) * 16384;

    // ---- phase a: read A0 + B0; stage B[t+1].h0 -> Bn; MFMA Q00
#pragma unroll
    for (int mi = 0; mi < 4; ++mi)
#pragma unroll
      for (int ks = 0; ks < 2; ++ks)
        af0[mi][ks] = rdfrag(Ap, wr * 128 + mi * 16 + lr, ks);
#pragma unroll
    for (int ni = 0; ni < 2; ++ni)
#pragma unroll
      for (int ks = 0; ks < 2; ++ks)
        bfr[ni][ks] = rdfrag(Bp, wc * 64 + ni * 16 + lr, ks);
    if (t + 1 < NT) stageB(t + 1, Bn, 0);
    S_BARRIER();
    __builtin_amdgcn_s_setprio(1);
#pragma unroll
    for (int mi = 0; mi < 4; ++mi)
#pragma unroll
      for (int ni = 0; ni < 2; ++ni)
#pragma unroll
        for (int ks = 0; ks < 2; ++ks)
          acc[mi][ni] = __builtin_amdgcn_mfma_f32_16x16x32_bf16(af0[mi][ks], bfr[ni][ks], acc[mi][ni], 0, 0, 0);
    __builtin_amdgcn_s_setprio(0);
    FENCE_LGKM0();
    S_BARRIER();

    // ---- phase b: read A1 (B0 kept in regs); stage B[t+1].h1; MFMA Q10
#pragma unroll
    for (int mi = 0; mi < 4; ++mi)
#pragma unroll
      for (int ks = 0; ks < 2; ++ks)
        af1[mi][ks] = rdfrag(Ap, wr * 128 + 64 + mi * 16 + lr, ks);
    if (t + 1 < NT) stageB(t + 1, Bn, 1);
    S_BARRIER();
    __builtin_amdgcn_s_setprio(1);
#pragma unroll
    for (int mi = 0; mi < 4; ++mi)
#pragma unroll
      for (int ni = 0; ni < 2; ++ni)
#pragma unroll
        for (int ks = 0; ks < 2; ++ks)
          acc[mi + 4][ni] = __builtin_amdgcn_mfma_f32_16x16x32_bf16(af1[mi][ks], bfr[ni][ks], acc[mi + 4][ni], 0, 0, 0);
    __builtin_amdgcn_s_setprio(0);
    FENCE_LGKM0();
    S_BARRIER();

    // ---- phase c: read B1 (overwrites B0 regs); stage A[t+2].h0; MFMA Q11
#pragma unroll
    for (int ni = 0; ni < 2; ++ni)
#pragma unroll
      for (int ks = 0; ks < 2; ++ks)
        bfr[ni][ks] = rdfrag(Bp, wc * 64 + (ni + 2) * 16 + lr, ks);
    if (t + 2 < NT) stageA(t + 2, Ap, 0);
    S_BARRIER();
    __builtin_amdgcn_s_setprio(1);
#pragma unroll
    for (int mi = 0; mi < 4; ++mi)
#pragma unroll
      for (int ni = 0; ni < 2; ++ni)
#pragma unroll
        for (int ks = 0; ks < 2; ++ks)
          acc[mi + 4][ni + 2] = __builtin_amdgcn_mfma_f32_16x16x32_bf16(af1[mi][ks], bfr[ni][ks], acc[mi + 4][ni + 2], 0, 0, 0);
    __builtin_amdgcn_s_setprio(0);
    FENCE_LGKM0();
    S_BARRIER();

    // ---- phase d: no ds_reads (A0,B1 in regs); stage A[t+2].h1; MFMA Q01
    if (t + 2 < NT) stageA(t + 2, Ap, 1);
    S_BARRIER();
    __builtin_amdgcn_s_setprio(1);
#pragma unroll
    for (int mi = 0; mi < 4; ++mi)
#pragma unroll
      for (int ni = 0; ni < 2; ++ni)
#pragma unroll
        for (int ks = 0; ks < 2; ++ks)
          acc[mi][ni + 2] = __builtin_amdgcn_mfma_f32_16x16x32_bf16(af0[mi][ks], bfr[ni][ks], acc[mi][ni + 2], 0, 0, 0);
    __builtin_amdgcn_s_setprio(0);
    if (t <= 13)      { FENCE_VM4(); }
    else if (t == 14) { FENCE_VM0(); }
    else              { FENCE_LGKM0(); }
    S_BARRIER();
  }
}

// ------------------------------------------------- fused Q/K/V projection GEMM
__global__ __launch_bounds__(512, 2) void qkv_gemm256_kernel(
    const uint16_t* __restrict__ XQ, const uint16_t* __restrict__ XK,
    const uint16_t* __restrict__ XV,
    const uint16_t* __restrict__ WQ, const uint16_t* __restrict__ WK,
    const uint16_t* __restrict__ WV,
    const float* __restrict__ bq, const float* __restrict__ bk,
    const float* __restrict__ bv,
    uint16_t* __restrict__ QS, uint16_t* __restrict__ KP,
    uint16_t* __restrict__ VP,
    float* __restrict__ pm, float* __restrict__ ps)
{
  extern __shared__ uint16_t smem[];           // As[2][16384] | Bs[2][16384] | sred
  uint16_t* As = smem;
  uint16_t* Bs = smem + 32768;
  float* sredm = (float*)(smem + 65536);       // [2][256]
  float* sreds = sredm + 512;

  const int tid = threadIdx.x;
  const int w = tid >> 6, l = tid & 63;
  const int lr = l & 15, kg = l >> 4;
  const int wr = w >> 2, wc = w & 3;           // 2x4 wave grid
  const int rsw = lr & 7;
  const int srcswz = ((tid >> 3) & 7) << 4;

  const int flat = blockIdx.y * 4 + blockIdx.x;
  const int swzf = (flat & 7) * 32 + (flat >> 3);
  const int brow = swzf >> 2, bcol = swzf & 3;
  const int z = blockIdx.z;

  const uint16_t* A = (z == 0) ? XQ : (z == 1) ? XK : XV;
  const uint16_t* W = (z == 0) ? WQ : (z == 1) ? WK : WV;
  const float* bias = (z == 0) ? bq : (z == 1) ? bk : bv;
  void* C          = (z == 0) ? (void*)QS : (z == 1) ? (void*)KP : (void*)VP;

  f32x4 acc[8][4];
#pragma unroll
  for (int i = 0; i < 8; ++i)
#pragma unroll
    for (int j = 0; j < 4; ++j) acc[i][j] = (f32x4){0.f, 0.f, 0.f, 0.f};

  gemm256_body(A, W, As, Bs, tid, w, brow * 256, bcol * 256, srcswz, rsw,
               lr, kg, wr, wc, acc);

  if (z == 0)
    gemm_epilogue<2>(acc, tid, l, lr, kg, wr, wc, brow, bcol, bias, C, pm, ps, sredm, sreds);
  else if (z == 1)
    gemm_epilogue<3>(acc, tid, l, lr, kg, wr, wc, brow, bcol, bias, C, pm, ps, sredm, sreds);
  else
    gemm_epilogue<0>(acc, tid, l, lr, kg, wr, wc, brow, bcol, bias, C, pm, ps, sredm, sreds);
}

// ------------------------------------------------- out-projection GEMM (batched W)
__global__ __launch_bounds__(512, 2) void gemm256_kernel(
    const uint16_t* __restrict__ A,
    const uint16_t* __restrict__ W,
    const float* __restrict__ bias,
    void* __restrict__ C)
{
  extern __shared__ uint16_t smem[];
  uint16_t* As = smem;
  uint16_t* Bs = smem + 32768;

  const int tid = threadIdx.x;
  const int w = tid >> 6, l = tid & 63;
  const int lr = l & 15, kg = l >> 4;
  const int wr = w >> 2, wc = w & 3;
  const int rsw = lr & 7;
  const int srcswz = ((tid >> 3) & 7) << 4;

  const int flat = blockIdx.y * 4 + blockIdx.x;
  const int swzf = (flat & 7) * 32 + (flat >> 3);
  const int brow = swzf >> 2, bcol = swzf & 3;

  const uint16_t* Wb = W + (size_t)(brow >> 4) * ((size_t)D_ * D_);

  f32x4 acc[8][4];
#pragma unroll
  for (int i = 0; i < 8; ++i)
#pragma unroll
    for (int j = 0; j < 4; ++j) acc[i][j] = (f32x4){0.f, 0.f, 0.f, 0.f};

  gemm256_body(A, Wb, As, Bs, tid, w, brow * 256, bcol * 256, srcswz, rsw,
               lr, kg, wr, wc, acc);

  gemm_epilogue<1>(acc, tid, l, lr, kg, wr, wc, brow, bcol, bias, C,
                   nullptr, nullptr, nullptr, nullptr);
}

// ------------------------------------------------- K column-softmax finalize
__global__ __launch_bounds__(256) void colstats_final_kernel(
    const float* __restrict__ pm, const float* __restrict__ ps,
    float* __restrict__ cmax, float* __restrict__ cinv)
{
  int f = blockIdx.x * 256 + threadIdx.x;     // b*1024 + col, 4096 total
  int b = f >> 10, col = f & 1023;
  float m = -1e30f;
  for (int c = 0; c < 16; ++c) m = fmaxf(m, pm[(size_t)(b * 16 + c) * D_ + col]);
  float s = 0.f;
  for (int c = 0; c < 16; ++c)
    s += ps[(size_t)(b * 16 + c) * D_ + col] * __expf(pm[(size_t)(b * 16 + c) * D_ + col] - m);
  cmax[f] = m;
  cinv[f] = 1.f / s;
}

// ------------------------------------------------- ctx[b,h] = softmax_n(K)^T @ V
// MFMA version: per 64-row subtile, compute w=exp(K-cm)*ci, 4x4 shfl-transpose
// (lanes l^16/l^32) into wt[d][n], vt[e][n] (bf16, [64][72] padded), then
// mfma_16x16x32: ctx[d][e] += sum_n w[n][d]*V[n][e].
__global__ __launch_bounds__(256) void ctx_partial_kernel(
    const uint16_t* __restrict__ kp, const uint16_t* __restrict__ vp,
    const float* __restrict__ cmax, const float* __restrict__ cinv,
    float* __restrict__ ctxp)
{
  __shared__ uint16_t wt[64][72];   // [d][n] bf16 weights (transposed, 16B rows)
  __shared__ uint16_t vt[64][72];   // [e][n] bf16 V (transposed)
  __shared__ float cm[64], ci[64];
  const int t = threadIdx.x;
  const int w = t >> 6, l = t & 63;
  const int lr = l & 15, p = l >> 4;
  const int nchunk = blockIdx.x, h = blockIdx.y, b = blockIdx.z;
  if (t < 64) {
    cm[t] = cmax[b * D_ + h * 64 + t];
    ci[t] = cinv[b * D_ + h * 64 + t];
  }
  __syncthreads();

  f32x4 acc[4];
#pragma unroll
  for (int i = 0; i < 4; ++i) acc[i] = (f32x4){0.f, 0.f, 0.f, 0.f};

  for (int tt = 0; tt < 8; ++tt) {
    int n0 = nchunk * 512 + tt * 64;
#pragma unroll
    for (int i = 0; i < 4; ++i) {
      int r = i * 16 + w * 4 + p;            // row n within subtile
      int c4 = lr * 4;                       // col d/e base
      size_t gi = (size_t)(b * N_ + n0 + r) * D_ + h * 64 + c4;
      union { uint16_t s[4]; uint2 u; } kk, vv;
      kk.u = *(const uint2*)(kp + gi);
      vv.u = *(const uint2*)(vp + gi);
      // softmax weights in fp32
      float a0 = __expf(bf2f(kk.s[0]) - cm[c4 + 0]) * ci[c4 + 0];
      float a1 = __expf(bf2f(kk.s[1]) - cm[c4 + 1]) * ci[c4 + 1];
      float a2 = __expf(bf2f(kk.s[2]) - cm[c4 + 2]) * ci[c4 + 2];
      float a3 = __expf(bf2f(kk.s[3]) - cm[c4 + 3]) * ci[c4 + 3];
      // 4x4 transpose across lanes (bit0 via xor16, bit1 via xor32)
      float s0 = __shfl_xor(a0, 16), s1 = __shfl_xor(a1, 16);
      float s2 = __shfl_xor(a2, 16), s3 = __shfl_xor(a3, 16);
      float c0 = (p & 1) ? s1 : a0, c1 = (p & 1) ? a1 : s0;
      float c2 = (p & 1) ? s3 : a2, c3 = (p & 1) ? a3 : s2;
      float S0 = __shfl_xor(c0, 32), S1 = __shfl_xor(c1, 32);
      float S2 = __shfl_xor(c2, 32), S3 = __shfl_xor(c3, 32);
      float e0 = (p & 2) ? S2 : c0, e1 = (p & 2) ? S3 : c1;
      float e2 = (p & 2) ? c2 : S0, e3 = (p & 2) ? c3 : S1;
      int rbase = i * 16 + w * 4;
      int cc = lr * 4 + p;
      *(uint2*)&wt[cc][rbase] = make_uint2(f2bf2(e0, e1), f2bf2(e2, e3));
      // V: same transpose on raw 16-bit payloads
      int b0 = vv.s[0], b1 = vv.s[1], b2 = vv.s[2], b3 = vv.s[3];
      int t0 = __shfl_xor(b0, 16), t1 = __shfl_xor(b1, 16);
      int t2 = __shfl_xor(b2, 16), t3 = __shfl_xor(b3, 16);
      int d0 = (p & 1) ? t1 : b0, d1 = (p & 1) ? b1 : t0;
      int d2 = (p & 1) ? t3 : b2, d3 = (p & 1) ? b3 : t2;
      int T0 = __shfl_xor(d0, 32), T1 = __shfl_xor(d1, 32);
      int T2 = __shfl_xor(d2, 32), T3 = __shfl_xor(d3, 32);
      uint32_t f0 = (p & 2) ? T2 : d0, f1 = (p & 2) ? T3 : d1;
      uint32_t f2v = (p & 2) ? d2 : T0, f3 = (p & 2) ? d3 : T1;
      *(uint2*)&vt[cc][rbase] =
          make_uint2((f0 & 0xFFFFu) | (f1 << 16), (f2v & 0xFFFFu) | (f3 << 16));
    }
    __syncthreads();
    // MFMA: wave w covers d rows w*16..w*16+15; K = 64 (2 k-slices)
    short8 af[2];
#pragma unroll
    for (int ks = 0; ks < 2; ++ks)
      af[ks] = *(const short8*)(&wt[w * 16 + lr][ks * 32 + p * 8]);
#pragma unroll
    for (int ni = 0; ni < 4; ++ni)
#pragma unroll
      for (int ks = 0; ks < 2; ++ks) {
        short8 bfv = *(const short8*)(&vt[ni * 16 + lr][ks * 32 + p * 8]);
        acc[ni] = __builtin_amdgcn_mfma_f32_16x16x32_bf16(af[ks], bfv, acc[ni], 0, 0, 0);
      }
    __syncthreads();
  }
  float* out = ctxp + (size_t)(nchunk * 64 + b * 16 + h) * 4096;
#pragma unroll
  for (int ni = 0; ni < 4; ++ni)
#pragma unroll
    for (int j = 0; j < 4; ++j)
      out[(w * 16 + p * 4 + j) * 64 + ni * 16 + lr] = acc[ni][j];
}

__global__ __launch_bounds__(256) void ctx_reduce_kernel(
    const float* __restrict__ ctxp, float* __restrict__ ctx)
{
  int o = (blockIdx.x * 256 + threadIdx.x) * 4;  // 262144 elems
  f32x4 s = (f32x4){0.f, 0.f, 0.f, 0.f};
  for (int c = 0; c < 8; ++c) s = s + *(const f32x4*)(ctxp + (size_t)c * 262144 + o);
  *(f32x4*)(ctx + o) = s;
}

// ---------------- W2T[b][o][h*64+d] = sum_e ctx[b,h][d][e] * Wo[o][h*64+e]
__global__ __launch_bounds__(256) void w2t_kernel(
    const float* __restrict__ ctx,      // [(b*16+h)][64 d][64 e]
    const uint16_t* __restrict__ wo,    // [1024 o][1024] bf16
    uint16_t* __restrict__ w2t)         // [b][1024 o][1024 j]
{
  __shared__ float ctxL[64][65];
  __shared__ float woL[64][65];
  int t = threadIdx.x;
  int otile = blockIdx.x, h = blockIdx.y, b = blockIdx.z;
  const float* csrc = ctx + (size_t)(b * 16 + h) * 4096;
#pragma unroll
  for (int i = 0; i < 4; ++i) {
    int idx = (i * 256 + t) * 4;
    int r = idx >> 6, c = idx & 63;
    f32x4 cv = *(const f32x4*)(csrc + idx);
    union { uint16_t s[4]; uint2 u; } wv;
    wv.u = *(const uint2*)(wo + (size_t)(otile * 64 + r) * D_ + h * 64 + c);
#pragma unroll
    for (int j = 0; j < 4; ++j) {
      ctxL[r][c + j] = cv[j];
      woL[r][c + j] = bf2f(wv.s[j]);
    }
  }
  __syncthreads();
  int ol = (t & 15) * 4, dl = (t >> 4) * 4;
  float acc[4][4];
#pragma unroll
  for (int i = 0; i < 4; ++i)
#pragma unroll
    for (int j = 0; j < 4; ++j) acc[i][j] = 0.f;
#pragma unroll 4
  for (int e = 0; e < 64; ++e) {
    float cv[4], wv[4];
#pragma unroll
    for (int i = 0; i < 4; ++i) { cv[i] = ctxL[dl + i][e]; wv[i] = woL[ol + i][e]; }
#pragma unroll
    for (int di = 0; di < 4; ++di)
#pragma unroll
      for (int oi = 0; oi < 4; ++oi) acc[di][oi] += cv[di] * wv[oi];
  }
  uint16_t* dst = w2t + (size_t)b * D_ * D_ + (size_t)(otile * 64) * D_ + h * 64;
#pragma unroll
  for (int oi = 0; oi < 4; ++oi) {
    union { uint16_t s[4]; uint2 u; } o4;
#pragma unroll
    for (int di = 0; di < 4; ++di) o4.s[di] = f2bf(acc[di][oi]);
    *(uint2*)(dst + (size_t)(ol + oi) * D_ + dl) = o4.u;
  }
}

// ---------------------------------------------------------------- launch
extern "C" void kernel_launch(void* const* d_in, const int* in_sizes, int n_in,
                              void* d_out, int out_size, void* d_ws, size_t ws_size,
                              hipStream_t stream)
{
  const float* q  = (const float*)d_in[0];
  const float* k  = (const float*)d_in[1];
  const float* v  = (const float*)d_in[2];
  const float* Wq = (const float*)d_in[3];
  const float* bq = (const float*)d_in[4];
  const float* Wk = (const float*)d_in[5];
  const float* bk = (const float*)d_in[6];
  const float* Wv = (const float*)d_in[7];
  const float* bv = (const float*)d_in[8];
  const float* Wo = (const float*)d_in[9];
  const float* bo = (const float*)d_in[10];

  char* ws = (char*)d_ws;
  const size_t XB = (size_t)M_ * D_ * 2;       // 32 MB bf16 activations
  const size_t WB = (size_t)D_ * D_ * 2;       // 2 MB bf16 weights
  uint16_t* XQ  = (uint16_t*)(ws);
  uint16_t* XK  = (uint16_t*)(ws + XB);
  uint16_t* XV  = (uint16_t*)(ws + 2 * XB);
  uint16_t* WQb = (uint16_t*)(ws + 3 * XB);
  uint16_t* WKb = (uint16_t*)(ws + 3 * XB + WB);
  uint16_t* WVb = (uint16_t*)(ws + 3 * XB + 2 * WB);
  uint16_t* WOb = (uint16_t*)(ws + 3 * XB + 3 * WB);
  uint16_t* QS  = (uint16_t*)(ws + 3 * XB + 4 * WB);   // softmaxed Q proj (bf16)
  uint16_t* KP  = (uint16_t*)(ws + 4 * XB + 4 * WB);
  uint16_t* VP  = (uint16_t*)(ws + 5 * XB + 4 * WB);
  // overlays (phase-ordered reuse):
  float* pm = (float*)d_out;                      // 256 KB (dead until out-GEMM)
  float* ps = (float*)((char*)d_out + (256 << 10)); // 256 KB
  float* cmax = (float*)XK;                       // 16 KB (XK dead after QKV GEMM)
  float* cinv = (float*)((char*)XK + (16 << 10)); // 16 KB
  float* ctxp = (float*)((char*)XK + (1 << 20));  // 8 MB
  float* ctx  = (float*)((char*)XK + (9 << 20));  // 1 MB
  uint16_t* W2T = XQ;                             // 8 MB (XQ dead after QKV GEMM)

  const size_t LDSB = 135168;                     // 128KB tiles + 4KB sred

  // 1) pack inputs + weights to bf16
  pack_bf16_kernel<<<dim3(1024, 7), 256, 0, stream>>>(
      q, k, v, Wq, Wk, Wv, Wo, XQ, XK, XV, WQb, WKb, WVb, WOb);

  // 2) fused Q/K/V projections (one launch, 768 blocks)
  qkv_gemm256_kernel<<<dim3(4, 64, 3), 512, LDSB, stream>>>(
      XQ, XK, XV, WQb, WKb, WVb, bq, bk, bv, QS, KP, VP, pm, ps);

  // 3) finalize K column-softmax stats (16 chunks of 256 rows per batch)
  colstats_final_kernel<<<16, 256, 0, stream>>>(pm, ps, cmax, cinv);

  // 4) ctx = softmax_n(K)^T V per head (MFMA)
  ctx_partial_kernel<<<dim3(8, H_, B_), 256, 0, stream>>>(KP, VP, cmax, cinv, ctxp);
  ctx_reduce_kernel<<<256, 256, 0, stream>>>(ctxp, ctx);

  // 5) fold block-diagonal ctx into output projection: W2T_b = (BD_b @ Wo^T)^T
  w2t_kernel<<<dim3(16, 16, 4), 256, 0, stream>>>(ctx, WOb, W2T);

  // 6) out = QS @ W2T_b^T + bo   (f32 out, per-batch weights)
  gemm256_kernel<<<dim3(4, 64), 512, LDSB, stream>>>(QS, W2T, bo, d_out);
}

// Round 11
// 258.123 us; speedup vs baseline: 1.0419x; 1.0141x over previous
//
#include <hip/hip_runtime.h>
#include <hip/hip_bf16.h>
#include <stdint.h>

// Problem shape (fixed by the reference): B=4, N=4096, D=1024, H=16, DK=64
#define B_  4
#define N_  4096
#define D_  1024
#define H_  16
#define DK_ 64
#define M_  (B_ * N_)   // 16384 rows

typedef __attribute__((ext_vector_type(8))) short  short8;   // 8 bf16 (4 VGPRs)
typedef __attribute__((ext_vector_type(4))) float  f32x4;
typedef __attribute__((ext_vector_type(4))) unsigned int u32x4;

__device__ __forceinline__ uint16_t f2bf(float f) {
  union { float f; uint32_t u; } v; v.f = f;
  uint32_t r = v.u + 0x7FFF + ((v.u >> 16) & 1);   // RNE
  return (uint16_t)(r >> 16);
}
__device__ __forceinline__ uint32_t f2bf2(float lo, float hi) {
  return (uint32_t)f2bf(lo) | ((uint32_t)f2bf(hi) << 16);
}
__device__ __forceinline__ float bf2f(uint16_t u) {
  union { uint32_t u; float f; } v; v.u = ((uint32_t)u) << 16;
  return v.f;
}

__device__ __forceinline__ void gload_lds16(const void* g, void* l) {
  __builtin_amdgcn_global_load_lds((const __attribute__((address_space(1))) void*)g,
                                   (__attribute__((address_space(3))) void*)l, 16, 0, 0);
}

#define S_BARRIER() __builtin_amdgcn_s_barrier()
#define FENCE_LGKM0() asm volatile("s_waitcnt lgkmcnt(0)" ::: "memory")
#define FENCE_VM4()   asm volatile("s_waitcnt vmcnt(4) lgkmcnt(0)" ::: "memory")
#define FENCE_VM0()   asm volatile("s_waitcnt vmcnt(0) lgkmcnt(0)" ::: "memory")

// ---------------------------------------------------------------- pack fp32->bf16
__global__ __launch_bounds__(256) void pack_bf16_kernel(
    const float* q, const float* k, const float* v,
    const float* wq, const float* wk, const float* wv, const float* wo,
    uint16_t* xq, uint16_t* xk, uint16_t* xv,
    uint16_t* bwq, uint16_t* bwk, uint16_t* bwv, uint16_t* bwo)
{
  const float* src; uint16_t* dst; int count;
  switch (blockIdx.y) {
    case 0: src = q;  dst = xq;  count = M_ * D_; break;
    case 1: src = k;  dst = xk;  count = M_ * D_; break;
    case 2: src = v;  dst = xv;  count = M_ * D_; break;
    case 3: src = wq; dst = bwq; count = D_ * D_; break;
    case 4: src = wk; dst = bwk; count = D_ * D_; break;
    case 5: src = wv; dst = bwv; count = D_ * D_; break;
    default: src = wo; dst = bwo; count = D_ * D_; break;
  }
  int base = blockIdx.x * 16384;               // 256 threads * 64 elems
  if (base >= count) return;                   // counts are multiples of 16384
  int t = threadIdx.x;
#pragma unroll
  for (int it = 0; it < 8; ++it) {
    int idx = base + it * 2048 + t * 8;
    f32x4 f0 = *(const f32x4*)(src + idx);
    f32x4 f1 = *(const f32x4*)(src + idx + 4);
    u32x4 o;
    o.x = f2bf2(f0.x, f0.y); o.y = f2bf2(f0.z, f0.w);
    o.z = f2bf2(f1.x, f1.y); o.w = f2bf2(f1.z, f1.w);
    *(u32x4*)(dst + idx) = o;
  }
}

// ---------------------------------------------------------------- shared epilogue
// C/D layout (m89-verified): col = lane&15, row = (lane>>4)*4 + reg
// EPI: 0 bf16 | 1 f32 | 2 bf16+row-softmax*0.5 | 3 bf16+col max/sumexp partials
template<int EPI>
__device__ __forceinline__ void gemm_epilogue(
    f32x4 (&acc)[8][4], int tid, int l, int lr, int kg, int wr, int wc,
    int brow, int bcol, const float* __restrict__ bias, void* __restrict__ C,
    float* __restrict__ pm, float* __restrict__ ps,
    float* sredm, float* sreds)
{
  if (EPI == 2) {
    float bv[4];
#pragma unroll
    for (int ni = 0; ni < 4; ++ni) bv[ni] = bias[bcol * 256 + wc * 64 + ni * 16 + lr];
#pragma unroll
    for (int mi = 0; mi < 8; ++mi) {
#pragma unroll
      for (int j = 0; j < 4; ++j) {
        float v0 = acc[mi][0][j] + bv[0];
        float v1 = acc[mi][1][j] + bv[1];
        float v2 = acc[mi][2][j] + bv[2];
        float v3 = acc[mi][3][j] + bv[3];
        float m = fmaxf(fmaxf(v0, v1), fmaxf(v2, v3));
#pragma unroll
        for (int o = 1; o < 16; o <<= 1) m = fmaxf(m, __shfl_xor(m, o));
        float p0 = __expf(v0 - m), p1 = __expf(v1 - m);
        float p2 = __expf(v2 - m), p3 = __expf(v3 - m);
        float s = (p0 + p1) + (p2 + p3);
#pragma unroll
        for (int o = 1; o < 16; o <<= 1) s += __shfl_xor(s, o);
        float sc = 0.5f / s;                    // * batch**-0.5 = 0.5
        int row = brow * 256 + wr * 128 + mi * 16 + kg * 4 + j;
        uint16_t* out = (uint16_t*)C + (size_t)row * D_ + bcol * 256 + wc * 64 + lr;
        out[0]  = f2bf(p0 * sc);
        out[16] = f2bf(p1 * sc);
        out[32] = f2bf(p2 * sc);
        out[48] = f2bf(p3 * sc);
      }
    }
  } else if (EPI == 3) {
#pragma unroll
    for (int ni = 0; ni < 4; ++ni) {
      int coll = wc * 64 + ni * 16 + lr;
      int col = bcol * 256 + coll;
      float bvn = bias[col];
      float vals[8][4];
      float m = -1e30f;
#pragma unroll
      for (int mi = 0; mi < 8; ++mi)
#pragma unroll
        for (int j = 0; j < 4; ++j) {
          float val = acc[mi][ni][j] + bvn;
          vals[mi][j] = val;
          m = fmaxf(m, val);
          int row = brow * 256 + wr * 128 + mi * 16 + kg * 4 + j;
          ((uint16_t*)C)[(size_t)row * D_ + col] = f2bf(val);
        }
      m = fmaxf(m, __shfl_xor(m, 16));
      m = fmaxf(m, __shfl_xor(m, 32));
      float s = 0.f;
#pragma unroll
      for (int mi = 0; mi < 8; ++mi)
#pragma unroll
        for (int j = 0; j < 4; ++j) s += __expf(vals[mi][j] - m);
      s += __shfl_xor(s, 16);
      s += __shfl_xor(s, 32);
      if (l < 16) {
        sredm[wr * 256 + coll] = m;
        sreds[wr * 256 + coll] = s;
      }
    }
    __syncthreads();
    if (tid < 256) {
      float m0 = sredm[tid], m1 = sredm[256 + tid];
      float s0 = sreds[tid], s1 = sreds[256 + tid];
      float m = fmaxf(m0, m1);
      float s = s0 * __expf(m0 - m) + s1 * __expf(m1 - m);
      pm[(size_t)brow * D_ + bcol * 256 + tid] = m;
      ps[(size_t)brow * D_ + bcol * 256 + tid] = s;
    }
  } else {
#pragma unroll
    for (int mi = 0; mi < 8; ++mi) {
#pragma unroll
      for (int ni = 0; ni < 4; ++ni) {
        int col = bcol * 256 + wc * 64 + ni * 16 + lr;
        float bv = bias[col];
#pragma unroll
        for (int j = 0; j < 4; ++j) {
          int row = brow * 256 + wr * 128 + mi * 16 + kg * 4 + j;
          float val = acc[mi][ni][j] + bv;
          if (EPI == 1) ((float*)C)[(size_t)row * D_ + col] = val;
          else          ((uint16_t*)C)[(size_t)row * D_ + col] = f2bf(val);
        }
      }
    }
  }
}

// ------------------------------------------------- shared 256x256 4-phase K-loop
// ONE barrier per phase: {reads; stage-issue; setprio MFMA; fence; barrier}.
// The old pre-MFMA barrier protected nothing (per-phase stage targets are
// disjoint from that phase's read regions; cross-phase hazards are covered by
// each phase's closing lgkm0+barrier) and serialized the LDS and MFMA pipes.
// Without it, a wave starts MFMA as soon as ITS reads return while others
// still issue reads -> cross-wave LDS||MFMA overlap; setprio arbitrates.
__device__ __forceinline__ void gemm256_body(
    const uint16_t* __restrict__ A, const uint16_t* __restrict__ Wb,
    uint16_t* As, uint16_t* Bs,
    int tid, int w, int arow0, int bcrow0, int srcswz, int rsw,
    int lr, int kg, int wr, int wc, f32x4 (&acc)[8][4])
{
  const int NT = 16;
  const uint16_t* gA[2][2];
  const uint16_t* gB[2][2];
  int lOff[2][2];
#pragma unroll
  for (int h = 0; h < 2; ++h)
#pragma unroll
    for (int i = 0; i < 2; ++i) {
      int lin = h * 16384 + i * 8192 + tid * 16;
      int src = lin ^ srcswz;
      size_t rowoff = (size_t)(src >> 7) * D_ + ((src & 127) >> 1);
      gA[h][i] = A + (size_t)arow0 * D_ + rowoff;
      gB[h][i] = Wb + (size_t)bcrow0 * D_ + rowoff;
      lOff[h][i] = h * 8192 + i * 4096 + w * 512;
    }
  auto stageA = [&](int kt, uint16_t* ldst, int h) {
    gload_lds16(gA[h][0] + kt * 64, ldst + lOff[h][0]);
    gload_lds16(gA[h][1] + kt * 64, ldst + lOff[h][1]);
  };
  auto stageB = [&](int kt, uint16_t* ldst, int h) {
    gload_lds16(gB[h][0] + kt * 64, ldst + lOff[h][0]);
    gload_lds16(gB[h][1] + kt * 64, ldst + lOff[h][1]);
  };
  auto rdfrag = [&](const uint16_t* tile, int row, int ks) -> short8 {
    return *(const short8*)(tile + row * 64 + ((((ks << 2) | kg) ^ rsw) << 3));
  };

  stageA(0, As, 0); stageA(0, As, 1);
  stageB(0, Bs, 0); stageB(0, Bs, 1);
  stageA(1, As + 16384, 0); stageA(1, As + 16384, 1);
  FENCE_VM4();
  S_BARRIER();

  short8 af0[4][2], af1[4][2], bfr[2][2];
  for (int t = 0; t < NT; ++t) {
    const int p = t & 1;
    uint16_t* Ap = As + p * 16384;
    uint16_t* Bp = Bs + p * 16384;
    uint16_t* Bn = Bs + (p ^ 1) * 16384;

    // ---- phase a: read A0 + B0; stage B[t+1].h0 -> Bn; MFMA Q00
#pragma unroll
    for (int mi = 0; mi < 4; ++mi)
#pragma unroll
      for (int ks = 0; ks < 2; ++ks)
        af0[mi][ks] = rdfrag(Ap, wr * 128 + mi * 16 + lr, ks);
#pragma unroll
    for (int ni = 0; ni < 2; ++ni)
#pragma unroll
      for (int ks = 0; ks < 2; ++ks)
        bfr[ni][ks] = rdfrag(Bp, wc * 64 + ni * 16 + lr, ks);
    if (t + 1 < NT) stageB(t + 1, Bn, 0);
    __builtin_amdgcn_s_setprio(1);
#pragma unroll
    for (int mi = 0; mi < 4; ++mi)
#pragma unroll
      for (int ni = 0; ni < 2; ++ni)
#pragma unroll
        for (int ks = 0; ks < 2; ++ks)
          acc[mi][ni] = __builtin_amdgcn_mfma_f32_16x16x32_bf16(af0[mi][ks], bfr[ni][ks], acc[mi][ni], 0, 0, 0);
    __builtin_amdgcn_s_setprio(0);
    FENCE_LGKM0();
    S_BARRIER();

    // ---- phase b: read A1 (B0 kept in regs); stage B[t+1].h1; MFMA Q10
#pragma unroll
    for (int mi = 0; mi < 4; ++mi)
#pragma unroll
      for (int ks = 0; ks < 2; ++ks)
        af1[mi][ks] = rdfrag(Ap, wr * 128 + 64 + mi * 16 + lr, ks);
    if (t + 1 < NT) stageB(t + 1, Bn, 1);
    __builtin_amdgcn_s_setprio(1);
#pragma unroll
    for (int mi = 0; mi < 4; ++mi)
#pragma unroll
      for (int ni = 0; ni < 2; ++ni)
#pragma unroll
        for (int ks = 0; ks < 2; ++ks)
          acc[mi + 4][ni] = __builtin_amdgcn_mfma_f32_16x16x32_bf16(af1[mi][ks], bfr[ni][ks], acc[mi + 4][ni], 0, 0, 0);
    __builtin_amdgcn_s_setprio(0);
    FENCE_LGKM0();
    S_BARRIER();

    // ---- phase c: read B1 (overwrites B0 regs); stage A[t+2].h0; MFMA Q11
#pragma unroll
    for (int ni = 0; ni < 2; ++ni)
#pragma unroll
      for (int ks = 0; ks < 2; ++ks)
        bfr[ni][ks] = rdfrag(Bp, wc * 64 + (ni + 2) * 16 + lr, ks);
    if (t + 2 < NT) stageA(t + 2, Ap, 0);
    __builtin_amdgcn_s_setprio(1);
#pragma unroll
    for (int mi = 0; mi < 4; ++mi)
#pragma unroll
      for (int ni = 0; ni < 2; ++ni)
#pragma unroll
        for (int ks = 0; ks < 2; ++ks)
          acc[mi + 4][ni + 2] = __builtin_amdgcn_mfma_f32_16x16x32_bf16(af1[mi][ks], bfr[ni][ks], acc[mi + 4][ni + 2], 0, 0, 0);
    __builtin_amdgcn_s_setprio(0);
    FENCE_LGKM0();
    S_BARRIER();

    // ---- phase d: no ds_reads (A0,B1 in regs); stage A[t+2].h1; MFMA Q01
    if (t + 2 < NT) stageA(t + 2, Ap, 1);
    __builtin_amdgcn_s_setprio(1);
#pragma unroll
    for (int mi = 0; mi < 4; ++mi)
#pragma unroll
      for (int ni = 0; ni < 2; ++ni)
#pragma unroll
        for (int ks = 0; ks < 2; ++ks)
          acc[mi][ni + 2] = __builtin_amdgcn_mfma_f32_16x16x32_bf16(af0[mi][ks], bfr[ni][ks], acc[mi][ni + 2], 0, 0, 0);
    __builtin_amdgcn_s_setprio(0);
    if (t <= 13)      { FENCE_VM4(); }
    else if (t == 14) { FENCE_VM0(); }
    else              { FENCE_LGKM0(); }
    S_BARRIER();
  }
}

// ------------------------------------------------- fused Q/K/V projection GEMM
__global__ __launch_bounds__(512, 2) void qkv_gemm256_kernel(
    const uint16_t* __restrict__ XQ, const uint16_t* __restrict__ XK,
    const uint16_t* __restrict__ XV,
    const uint16_t* __restrict__ WQ, const uint16_t* __restrict__ WK,
    const uint16_t* __restrict__ WV,
    const float* __restrict__ bq, const float* __restrict__ bk,
    const float* __restrict__ bv,
    uint16_t* __restrict__ QS, uint16_t* __restrict__ KP,
    uint16_t* __restrict__ VP,
    float* __restrict__ pm, float* __restrict__ ps)
{
  extern __shared__ uint16_t smem[];           // As[2][16384] | Bs[2][16384] | sred
  uint16_t* As = smem;
  uint16_t* Bs = smem + 32768;
  float* sredm = (float*)(smem + 65536);       // [2][256]
  float* sreds = sredm + 512;

  const int tid = threadIdx.x;
  const int w = tid >> 6, l = tid & 63;
  const int lr = l & 15, kg = l >> 4;
  const int wr = w >> 2, wc = w & 3;           // 2x4 wave grid
  const int rsw = lr & 7;
  const int srcswz = ((tid >> 3) & 7) << 4;

  const int flat = blockIdx.y * 4 + blockIdx.x;
  const int swzf = (flat & 7) * 32 + (flat >> 3);
  const int brow = swzf >> 2, bcol = swzf & 3;
  const int z = blockIdx.z;

  const uint16_t* A = (z == 0) ? XQ : (z == 1) ? XK : XV;
  const uint16_t* W = (z == 0) ? WQ : (z == 1) ? WK : WV;
  const float* bias = (z == 0) ? bq : (z == 1) ? bk : bv;
  void* C          = (z == 0) ? (void*)QS : (z == 1) ? (void*)KP : (void*)VP;

  f32x4 acc[8][4];
#pragma unroll
  for (int i = 0; i < 8; ++i)
#pragma unroll
    for (int j = 0; j < 4; ++j) acc[i][j] = (f32x4){0.f, 0.f, 0.f, 0.f};

  gemm256_body(A, W, As, Bs, tid, w, brow * 256, bcol * 256, srcswz, rsw,
               lr, kg, wr, wc, acc);

  if (z == 0)
    gemm_epilogue<2>(acc, tid, l, lr, kg, wr, wc, brow, bcol, bias, C, pm, ps, sredm, sreds);
  else if (z == 1)
    gemm_epilogue<3>(acc, tid, l, lr, kg, wr, wc, brow, bcol, bias, C, pm, ps, sredm, sreds);
  else
    gemm_epilogue<0>(acc, tid, l, lr, kg, wr, wc, brow, bcol, bias, C, pm, ps, sredm, sreds);
}

// ------------------------------------------------- out-projection GEMM (batched W)
__global__ __launch_bounds__(512, 2) void gemm256_kernel(
    const uint16_t* __restrict__ A,
    const uint16_t* __restrict__ W,
    const float* __restrict__ bias,
    void* __restrict__ C)
{
  extern __shared__ uint16_t smem[];
  uint16_t* As = smem;
  uint16_t* Bs = smem + 32768;

  const int tid = threadIdx.x;
  const int w = tid >> 6, l = tid & 63;
  const int lr = l & 15, kg = l >> 4;
  const int wr = w >> 2, wc = w & 3;
  const int rsw = lr & 7;
  const int srcswz = ((tid >> 3) & 7) << 4;

  const int flat = blockIdx.y * 4 + blockIdx.x;
  const int swzf = (flat & 7) * 32 + (flat >> 3);
  const int brow = swzf >> 2, bcol = swzf & 3;

  const uint16_t* Wb = W + (size_t)(brow >> 4) * ((size_t)D_ * D_);

  f32x4 acc[8][4];
#pragma unroll
  for (int i = 0; i < 8; ++i)
#pragma unroll
    for (int j = 0; j < 4; ++j) acc[i][j] = (f32x4){0.f, 0.f, 0.f, 0.f};

  gemm256_body(A, Wb, As, Bs, tid, w, brow * 256, bcol * 256, srcswz, rsw,
               lr, kg, wr, wc, acc);

  gemm_epilogue<1>(acc, tid, l, lr, kg, wr, wc, brow, bcol, bias, C,
                   nullptr, nullptr, nullptr, nullptr);
}

// ------------------------------------------------- K column-softmax finalize
__global__ __launch_bounds__(256) void colstats_final_kernel(
    const float* __restrict__ pm, const float* __restrict__ ps,
    float* __restrict__ cmax, float* __restrict__ cinv)
{
  int f = blockIdx.x * 256 + threadIdx.x;     // b*1024 + col, 4096 total
  int b = f >> 10, col = f & 1023;
  float m = -1e30f;
  for (int c = 0; c < 16; ++c) m = fmaxf(m, pm[(size_t)(b * 16 + c) * D_ + col]);
  float s = 0.f;
  for (int c = 0; c < 16; ++c)
    s += ps[(size_t)(b * 16 + c) * D_ + col] * __expf(pm[(size_t)(b * 16 + c) * D_ + col] - m);
  cmax[f] = m;
  cinv[f] = 1.f / s;
}

// ------------------------------------------------- ctx[b,h] = softmax_n(K)^T @ V
// MFMA version (round-10-proven): shfl 4x4 transpose -> bf16 LDS -> 16x16x32.
__global__ __launch_bounds__(256) void ctx_partial_kernel(
    const uint16_t* __restrict__ kp, const uint16_t* __restrict__ vp,
    const float* __restrict__ cmax, const float* __restrict__ cinv,
    float* __restrict__ ctxp)
{
  __shared__ uint16_t wt[64][72];   // [d][n] bf16 weights (transposed, 16B rows)
  __shared__ uint16_t vt[64][72];   // [e][n] bf16 V (transposed)
  __shared__ float cm[64], ci[64];
  const int t = threadIdx.x;
  const int w = t >> 6, l = t & 63;
  const int lr = l & 15, p = l >> 4;
  const int nchunk = blockIdx.x, h = blockIdx.y, b = blockIdx.z;
  if (t < 64) {
    cm[t] = cmax[b * D_ + h * 64 + t];
    ci[t] = cinv[b * D_ + h * 64 + t];
  }
  __syncthreads();

  f32x4 acc[4];
#pragma unroll
  for (int i = 0; i < 4; ++i) acc[i] = (f32x4){0.f, 0.f, 0.f, 0.f};

  for (int tt = 0; tt < 8; ++tt) {
    int n0 = nchunk * 512 + tt * 64;
#pragma unroll
    for (int i = 0; i < 4; ++i) {
      int r = i * 16 + w * 4 + p;            // row n within subtile
      int c4 = lr * 4;                       // col d/e base
      size_t gi = (size_t)(b * N_ + n0 + r) * D_ + h * 64 + c4;
      union { uint16_t s[4]; uint2 u; } kk, vv;
      kk.u = *(const uint2*)(kp + gi);
      vv.u = *(const uint2*)(vp + gi);
      float a0 = __expf(bf2f(kk.s[0]) - cm[c4 + 0]) * ci[c4 + 0];
      float a1 = __expf(bf2f(kk.s[1]) - cm[c4 + 1]) * ci[c4 + 1];
      float a2 = __expf(bf2f(kk.s[2]) - cm[c4 + 2]) * ci[c4 + 2];
      float a3 = __expf(bf2f(kk.s[3]) - cm[c4 + 3]) * ci[c4 + 3];
      float s0 = __shfl_xor(a0, 16), s1 = __shfl_xor(a1, 16);
      float s2 = __shfl_xor(a2, 16), s3 = __shfl_xor(a3, 16);
      float c0 = (p & 1) ? s1 : a0, c1 = (p & 1) ? a1 : s0;
      float c2 = (p & 1) ? s3 : a2, c3 = (p & 1) ? a3 : s2;
      float S0 = __shfl_xor(c0, 32), S1 = __shfl_xor(c1, 32);
      float S2 = __shfl_xor(c2, 32), S3 = __shfl_xor(c3, 32);
      float e0 = (p & 2) ? S2 : c0, e1 = (p & 2) ? S3 : c1;
      float e2 = (p & 2) ? c2 : S0, e3 = (p & 2) ? c3 : S1;
      int rbase = i * 16 + w * 4;
      int cc = lr * 4 + p;
      *(uint2*)&wt[cc][rbase] = make_uint2(f2bf2(e0, e1), f2bf2(e2, e3));
      int b0 = vv.s[0], b1 = vv.s[1], b2 = vv.s[2], b3 = vv.s[3];
      int t0 = __shfl_xor(b0, 16), t1 = __shfl_xor(b1, 16);
      int t2 = __shfl_xor(b2, 16), t3 = __shfl_xor(b3, 16);
      int d0 = (p & 1) ? t1 : b0, d1 = (p & 1) ? b1 : t0;
      int d2 = (p & 1) ? t3 : b2, d3 = (p & 1) ? b3 : t2;
      int T0 = __shfl_xor(d0, 32), T1 = __shfl_xor(d1, 32);
      int T2 = __shfl_xor(d2, 32), T3 = __shfl_xor(d3, 32);
      uint32_t f0 = (p & 2) ? T2 : d0, f1 = (p & 2) ? T3 : d1;
      uint32_t f2v = (p & 2) ? d2 : T0, f3 = (p & 2) ? d3 : T1;
      *(uint2*)&vt[cc][rbase] =
          make_uint2((f0 & 0xFFFFu) | (f1 << 16), (f2v & 0xFFFFu) | (f3 << 16));
    }
    __syncthreads();
    short8 af[2];
#pragma unroll
    for (int ks = 0; ks < 2; ++ks)
      af[ks] = *(const short8*)(&wt[w * 16 + lr][ks * 32 + p * 8]);
#pragma unroll
    for (int ni = 0; ni < 4; ++ni)
#pragma unroll
      for (int ks = 0; ks < 2; ++ks) {
        short8 bfv = *(const short8*)(&vt[ni * 16 + lr][ks * 32 + p * 8]);
        acc[ni] = __builtin_amdgcn_mfma_f32_16x16x32_bf16(af[ks], bfv, acc[ni], 0, 0, 0);
      }
    __syncthreads();
  }
  float* out = ctxp + (size_t)(nchunk * 64 + b * 16 + h) * 4096;
#pragma unroll
  for (int ni = 0; ni < 4; ++ni)
#pragma unroll
    for (int j = 0; j < 4; ++j)
      out[(w * 16 + p * 4 + j) * 64 + ni * 16 + lr] = acc[ni][j];
}

__global__ __launch_bounds__(256) void ctx_reduce_kernel(
    const float* __restrict__ ctxp, float* __restrict__ ctx)
{
  int o = (blockIdx.x * 256 + threadIdx.x) * 4;  // 262144 elems
  f32x4 s = (f32x4){0.f, 0.f, 0.f, 0.f};
  for (int c = 0; c < 8; ++c) s = s + *(const f32x4*)(ctxp + (size_t)c * 262144 + o);
  *(f32x4*)(ctx + o) = s;
}

// ---------------- W2T[b][o][h*64+d] = sum_e ctx[b,h][d][e] * Wo[o][h*64+e]
__global__ __launch_bounds__(256) void w2t_kernel(
    const float* __restrict__ ctx,      // [(b*16+h)][64 d][64 e]
    const uint16_t* __restrict__ wo,    // [1024 o][1024] bf16
    uint16_t* __restrict__ w2t)         // [b][1024 o][1024 j]
{
  __shared__ float ctxL[64][65];
  __shared__ float woL[64][65];
  int t = threadIdx.x;
  int otile = blockIdx.x, h = blockIdx.y, b = blockIdx.z;
  const float* csrc = ctx + (size_t)(b * 16 + h) * 4096;
#pragma unroll
  for (int i = 0; i < 4; ++i) {
    int idx = (i * 256 + t) * 4;
    int r = idx >> 6, c = idx & 63;
    f32x4 cv = *(const f32x4*)(csrc + idx);
    union { uint16_t s[4]; uint2 u; } wv;
    wv.u = *(const uint2*)(wo + (size_t)(otile * 64 + r) * D_ + h * 64 + c);
#pragma unroll
    for (int j = 0; j < 4; ++j) {
      ctxL[r][c + j] = cv[j];
      woL[r][c + j] = bf2f(wv.s[j]);
    }
  }
  __syncthreads();
  int ol = (t & 15) * 4, dl = (t >> 4) * 4;
  float acc[4][4];
#pragma unroll
  for (int i = 0; i < 4; ++i)
#pragma unroll
    for (int j = 0; j < 4; ++j) acc[i][j] = 0.f;
#pragma unroll 4
  for (int e = 0; e < 64; ++e) {
    float cv[4], wv[4];
#pragma unroll
    for (int i = 0; i < 4; ++i) { cv[i] = ctxL[dl + i][e]; wv[i] = woL[ol + i][e]; }
#pragma unroll
    for (int di = 0; di < 4; ++di)
#pragma unroll
      for (int oi = 0; oi < 4; ++oi) acc[di][oi] += cv[di] * wv[oi];
  }
  uint16_t* dst = w2t + (size_t)b * D_ * D_ + (size_t)(otile * 64) * D_ + h * 64;
#pragma unroll
  for (int oi = 0; oi < 4; ++oi) {
    union { uint16_t s[4]; uint2 u; } o4;
#pragma unroll
    for (int di = 0; di < 4; ++di) o4.s[di] = f2bf(acc[di][oi]);
    *(uint2*)(dst + (size_t)(ol + oi) * D_ + dl) = o4.u;
  }
}

// ---------------------------------------------------------------- launch
extern "C" void kernel_launch(void* const* d_in, const int* in_sizes, int n_in,
                              void* d_out, int out_size, void* d_ws, size_t ws_size,
                              hipStream_t stream)
{
  const float* q  = (const float*)d_in[0];
  const float* k  = (const float*)d_in[1];
  const float* v  = (const float*)d_in[2];
  const float* Wq = (const float*)d_in[3];
  const float* bq = (const float*)d_in[4];
  const float* Wk = (const float*)d_in[5];
  const float* bk = (const float*)d_in[6];
  const float* Wv = (const float*)d_in[7];
  const float* bv = (const float*)d_in[8];
  const float* Wo = (const float*)d_in[9];
  const float* bo = (const float*)d_in[10];

  char* ws = (char*)d_ws;
  const size_t XB = (size_t)M_ * D_ * 2;       // 32 MB bf16 activations
  const size_t WB = (size_t)D_ * D_ * 2;       // 2 MB bf16 weights
  uint16_t* XQ  = (uint16_t*)(ws);
  uint16_t* XK  = (uint16_t*)(ws + XB);
  uint16_t* XV  = (uint16_t*)(ws + 2 * XB);
  uint16_t* WQb = (uint16_t*)(ws + 3 * XB);
  uint16_t* WKb = (uint16_t*)(ws + 3 * XB + WB);
  uint16_t* WVb = (uint16_t*)(ws + 3 * XB + 2 * WB);
  uint16_t* WOb = (uint16_t*)(ws + 3 * XB + 3 * WB);
  uint16_t* QS  = (uint16_t*)(ws + 3 * XB + 4 * WB);   // softmaxed Q proj (bf16)
  uint16_t* KP  = (uint16_t*)(ws + 4 * XB + 4 * WB);
  uint16_t* VP  = (uint16_t*)(ws + 5 * XB + 4 * WB);
  // overlays (phase-ordered reuse):
  float* pm = (float*)d_out;                      // 256 KB (dead until out-GEMM)
  float* ps = (float*)((char*)d_out + (256 << 10)); // 256 KB
  float* cmax = (float*)XK;                       // 16 KB (XK dead after QKV GEMM)
  float* cinv = (float*)((char*)XK + (16 << 10)); // 16 KB
  float* ctxp = (float*)((char*)XK + (1 << 20));  // 8 MB
  float* ctx  = (float*)((char*)XK + (9 << 20));  // 1 MB
  uint16_t* W2T = XQ;                             // 8 MB (XQ dead after QKV GEMM)

  const size_t LDSB = 135168;                     // 128KB tiles + 4KB sred

  // 1) pack inputs + weights to bf16
  pack_bf16_kernel<<<dim3(1024, 7), 256, 0, stream>>>(
      q, k, v, Wq, Wk, Wv, Wo, XQ, XK, XV, WQb, WKb, WVb, WOb);

  // 2) fused Q/K/V projections (one launch, 768 blocks)
  qkv_gemm256_kernel<<<dim3(4, 64, 3), 512, LDSB, stream>>>(
      XQ, XK, XV, WQb, WKb, WVb, bq, bk, bv, QS, KP, VP, pm, ps);

  // 3) finalize K column-softmax stats (16 chunks of 256 rows per batch)
  colstats_final_kernel<<<16, 256, 0, stream>>>(pm, ps, cmax, cinv);

  // 4) ctx = softmax_n(K)^T V per head (MFMA)
  ctx_partial_kernel<<<dim3(8, H_, B_), 256, 0, stream>>>(KP, VP, cmax, cinv, ctxp);
  ctx_reduce_kernel<<<256, 256, 0, stream>>>(ctxp, ctx);

  // 5) fold block-diagonal ctx into output projection: W2T_b = (BD_b @ Wo^T)^T
  w2t_kernel<<<dim3(16, 16, 4), 256, 0, stream>>>(ctx, WOb, W2T);

  // 6) out = QS @ W2T_b^T + bo   (f32 out, per-batch weights)
  gemm256_kernel<<<dim3(4, 64), 512, LDSB, stream>>>(QS, W2T, bo, d_out);
}